// Round 2
// baseline (815.946 us; speedup 1.0000x reference)
//
#include <hip/hip_runtime.h>
#include <type_traits>
#include <utility>
#include <stdint.h>
#include <stddef.h>

#define TOKENS 8192
#define CDIM 2048
#define FDIM 8192
#define EPSV 1.1920929e-07f

typedef __attribute__((ext_vector_type(8))) short short8;
typedef __attribute__((ext_vector_type(8))) __bf16 bf16x8;
typedef __attribute__((ext_vector_type(4))) float floatx4;

// Detect which operand typing this clang uses for the gfx950 bf16 MFMA builtin.
template <typename V, typename = void> struct CanMfma : std::false_type {};
template <typename V>
struct CanMfma<V, std::void_t<decltype(__builtin_amdgcn_mfma_f32_16x16x32_bf16(
    std::declval<V>(), std::declval<V>(), std::declval<floatx4>(), 0, 0, 0))>>
    : std::true_type {};
using frag_t = std::conditional_t<CanMfma<short8>::value, short8, bf16x8>;

__device__ __forceinline__ floatx4 mfma_bf16(frag_t a, frag_t b, floatx4 c) {
    return __builtin_amdgcn_mfma_f32_16x16x32_bf16(a, b, c, 0, 0, 0);
}

// round-to-nearest-even f32 -> bf16
__device__ __forceinline__ unsigned short f2bf(float f) {
    unsigned int u = __float_as_uint(f);
    u += 0x7fffu + ((u >> 16) & 1u);
    return (unsigned short)(u >> 16);
}

__global__ void zero_kernel(int* p) { if (threadIdx.x == 0) *p = 0; }

__global__ __launch_bounds__(256) void cvt_kernel(const float* __restrict__ src,
                                                  unsigned short* __restrict__ dst, int n4) {
    int i = blockIdx.x * 256 + threadIdx.x;
    if (i < n4) {
        float4 v = ((const float4*)src)[i];
        ushort4 o;
        o.x = f2bf(v.x); o.y = f2bf(v.y); o.z = f2bf(v.z); o.w = f2bf(v.w);
        ((ushort4*)dst)[i] = o;
    }
}

// Per token: router logit, sigmoid mask, RMSNorm; compact selected tokens into
// Xn (bf16) via atomic counter; unselected tokens get out = x (residual only).
__global__ __launch_bounds__(256) void router_kernel(
    const float* __restrict__ x, const float* __restrict__ wr,
    float* __restrict__ out, unsigned short* __restrict__ Xn,
    int* __restrict__ idx, float* __restrict__ mv, int* __restrict__ cnt)
{
    const int token = blockIdx.x;
    const int tid = threadIdx.x;
    const float4* xr = (const float4*)(x + (size_t)token * CDIM);
    const float4* w4 = (const float4*)wr;
    float4 a0 = xr[tid];
    float4 a1 = xr[tid + 256];
    float4 b0 = w4[tid];
    float4 b1 = w4[tid + 256];
    float ss = a0.x*a0.x + a0.y*a0.y + a0.z*a0.z + a0.w*a0.w
             + a1.x*a1.x + a1.y*a1.y + a1.z*a1.z + a1.w*a1.w;
    float dt = a0.x*b0.x + a0.y*b0.y + a0.z*b0.z + a0.w*b0.w
             + a1.x*b1.x + a1.y*b1.y + a1.z*b1.z + a1.w*b1.w;
    #pragma unroll
    for (int off = 32; off > 0; off >>= 1) {
        ss += __shfl_down(ss, off);
        dt += __shfl_down(dt, off);
    }
    __shared__ float red_ss[4], red_dt[4];
    __shared__ float s_rms;
    __shared__ int s_pos;
    const int wave = tid >> 6;
    if ((tid & 63) == 0) { red_ss[wave] = ss; red_dt[wave] = dt; }
    __syncthreads();
    if (tid == 0) {
        float S = red_ss[0] + red_ss[1] + red_ss[2] + red_ss[3];
        float D = red_dt[0] + red_dt[1] + red_dt[2] + red_dt[3];
        float prob = 1.0f / (1.0f + expf(-D));
        s_rms = 1.0f / sqrtf(S * (1.0f / (float)CDIM) + EPSV);
        int pos = -1;
        if (prob > 0.5f) {
            pos = atomicAdd(cnt, 1);
            idx[pos] = token;
            mv[pos] = (1.0f + prob) - prob;  // replicate STE mask_i rounding exactly
        }
        s_pos = pos;
    }
    __syncthreads();
    const float rms = s_rms;
    const int pos = s_pos;
    if (pos >= 0) {
        ushort4* xp = (ushort4*)(Xn + (size_t)pos * CDIM);
        ushort4 o;
        o.x = f2bf(a0.x * rms); o.y = f2bf(a0.y * rms); o.z = f2bf(a0.z * rms); o.w = f2bf(a0.w * rms);
        xp[tid] = o;
        o.x = f2bf(a1.x * rms); o.y = f2bf(a1.y * rms); o.z = f2bf(a1.z * rms); o.w = f2bf(a1.w * rms);
        xp[tid + 256] = o;
    } else {
        float4* op = (float4*)(out + (size_t)token * CDIM);
        op[tid] = a0;
        op[tid + 256] = a1;
    }
}

// C[m][n] = sum_k A[m][k]*B[n][k], A:[M][K] bf16 row-major (compacted rows),
// B:[N][K] bf16 row-major. 128x128 tile, BK=64, 4 waves 2x2, 4x4 MFMA 16x16x32.
// global_load_lds(16B) staging; XOR swizzle applied on the GLOBAL address side.
//
// Block raster: m-FASTEST (m0 = blockIdx.x). Consecutive blocks share one
// B-panel (L2-resident) and stream A; A and B each leave HBM ~once instead of
// B being re-streamed per m-row (round-1 counters: FETCH 515 MB @1.6 TB/s,
// 4x cold size -> HBM-latency-bound, MfmaUtil 18.8%).
// MODE 1: Hout[m][n] = bf16(relu(acc)^2).  MODE 2: out scatter + residual.
template <int K, int MODE, int LDO>
__global__ __launch_bounds__(256) void gemm_bt(
    const unsigned short* __restrict__ A,
    const unsigned short* __restrict__ B,
    unsigned short* __restrict__ Hout,
    float* __restrict__ out,
    const float* __restrict__ xres,
    const int* __restrict__ idx,
    const float* __restrict__ mv,
    const int* __restrict__ cntp)
{
    const int cnt = *cntp;
    const int m0 = blockIdx.x * 128;   // m-fastest raster
    if (m0 >= cnt) return;
    const int n0 = blockIdx.y * 128;

    __shared__ alignas(16) unsigned short lA[128 * 64];
    __shared__ alignas(16) unsigned short lB[128 * 64];

    const int tid = threadIdx.x;
    const int wave = tid >> 6;
    const int lane = tid & 63;
    const int wm = (wave >> 1) * 64;
    const int wn = (wave & 1) * 64;
    const int quad = lane >> 4;
    const int l16 = lane & 15;

    // staging: wave w, issue p covers rows p*32+w*8 .. +8; lane i -> row +i/8,
    // global 16B chunk (i&7)^(i/8) (swizzle), LDS chunk i&7 (hardware lane order)
    const int srow = lane >> 3;
    const int schunk = (lane & 7) ^ srow;

    const unsigned short* ap[4];
    const unsigned short* bp[4];
    #pragma unroll
    for (int p = 0; p < 4; ++p) {
        const int r = p * 32 + wave * 8 + srow;
        ap[p] = A + (size_t)(m0 + r) * K + schunk * 8;
        bp[p] = B + (size_t)(n0 + r) * K + schunk * 8;
    }

    floatx4 acc[4][4] = {};

    for (int kt = 0; kt < K / 64; ++kt) {
        #pragma unroll
        for (int p = 0; p < 4; ++p) {
            __builtin_amdgcn_global_load_lds(
                (__attribute__((address_space(1))) void*)ap[p],
                (__attribute__((address_space(3))) void*)&lA[(p * 32 + wave * 8) * 64],
                16, 0, 0);
            __builtin_amdgcn_global_load_lds(
                (__attribute__((address_space(1))) void*)bp[p],
                (__attribute__((address_space(3))) void*)&lB[(p * 32 + wave * 8) * 64],
                16, 0, 0);
            ap[p] += 64;
            bp[p] += 64;
        }
        __syncthreads();  // drains vmcnt before LDS reads
        #pragma unroll
        for (int s = 0; s < 2; ++s) {
            frag_t af[4], bfv[4];
            #pragma unroll
            for (int t = 0; t < 4; ++t) {
                const int ra = wm + t * 16 + l16;
                const int ca = ((s * 4 + quad) ^ (ra & 7)) * 8;
                af[t] = *(const frag_t*)&lA[ra * 64 + ca];
                const int rb = wn + t * 16 + l16;
                const int cb = ((s * 4 + quad) ^ (rb & 7)) * 8;
                bfv[t] = *(const frag_t*)&lB[rb * 64 + cb];
            }
            #pragma unroll
            for (int tm = 0; tm < 4; ++tm)
                #pragma unroll
                for (int tn = 0; tn < 4; ++tn)
                    acc[tm][tn] = mfma_bf16(af[tm], bfv[tn], acc[tm][tn]);
        }
        __syncthreads();
    }

    // C/D layout (verified m89/m91): col(n) = lane&15, row(m) = quad*4 + reg
    if (MODE == 1) {
        #pragma unroll
        for (int tm = 0; tm < 4; ++tm) {
            const int gm = m0 + wm + tm * 16 + quad * 4;
            #pragma unroll
            for (int tn = 0; tn < 4; ++tn) {
                const int gn = n0 + wn + tn * 16 + l16;
                #pragma unroll
                for (int v = 0; v < 4; ++v) {
                    float h = fmaxf(acc[tm][tn][v], 0.0f);  // fmax eats NaN pad rows too
                    Hout[(size_t)(gm + v) * LDO + gn] = f2bf(h * h);
                }
            }
        }
    } else {
        #pragma unroll
        for (int tm = 0; tm < 4; ++tm) {
            const int gmb = m0 + wm + tm * 16 + quad * 4;
            #pragma unroll
            for (int v = 0; v < 4; ++v) {
                const int gm = gmb + v;
                if (gm < cnt) {  // never read poisoned idx/mv beyond cnt
                    const int token = idx[gm];
                    const float scale = mv[gm];
                    #pragma unroll
                    for (int tn = 0; tn < 4; ++tn) {
                        const int gn = n0 + wn + tn * 16 + l16;
                        const size_t o = (size_t)token * LDO + gn;
                        out[o] = xres[o] + scale * acc[tm][tn][v];
                    }
                }
            }
        }
    }
}

extern "C" void kernel_launch(void* const* d_in, const int* in_sizes, int n_in,
                              void* d_out, int out_size, void* d_ws, size_t ws_size,
                              hipStream_t stream)
{
    const float* x   = (const float*)d_in[0];
    const float* wfc = (const float*)d_in[1];
    const float* wpr = (const float*)d_in[2];
    const float* wrt = (const float*)d_in[3];
    float* out = (float*)d_out;

    // ws layout (bytes): [cnt 256][idx 32K][mv 32K][Xn 32M][Wfc 32M][Wpr 32M][H 128M]
    char* ws = (char*)d_ws;
    int*   cnt = (int*)ws;
    int*   idx = (int*)(ws + 256);
    float* mv  = (float*)(ws + 256 + 32768);
    unsigned short* Xn  = (unsigned short*)(ws + 65792);
    unsigned short* Wfc = (unsigned short*)(ws + 65792 + 33554432ULL);
    unsigned short* Wpr = (unsigned short*)(ws + 65792 + 67108864ULL);
    unsigned short* H   = (unsigned short*)(ws + 65792 + 100663296ULL);

    zero_kernel<<<1, 64, 0, stream>>>(cnt);
    cvt_kernel<<<(FDIM * CDIM / 4) / 256, 256, 0, stream>>>(wfc, Wfc, FDIM * CDIM / 4);
    cvt_kernel<<<(CDIM * FDIM / 4) / 256, 256, 0, stream>>>(wpr, Wpr, CDIM * FDIM / 4);
    router_kernel<<<TOKENS, 256, 0, stream>>>(x, wrt, out, Xn, idx, mv, cnt);
    // GEMM1: H[m][f] = relu(Xn @ Wfc^T)^2, M=cnt (<=8192), N=8192, K=2048
    // grid: x = m-panels (fast), y = n-panels
    gemm_bt<CDIM, 1, FDIM><<<dim3(TOKENS / 128, FDIM / 128), 256, 0, stream>>>(
        Xn, Wfc, H, nullptr, nullptr, nullptr, nullptr, cnt);
    // GEMM2: out[token][c] = x + mask_i * (H @ Wpr^T), M=cnt, N=2048, K=8192
    gemm_bt<FDIM, 2, CDIM><<<dim3(TOKENS / 128, CDIM / 128), 256, 0, stream>>>(
        H, Wpr, nullptr, out, x, idx, mv, cnt);
}

// Round 3
// 704.853 us; speedup vs baseline: 1.1576x; 1.1576x over previous
//
#include <hip/hip_runtime.h>
#include <type_traits>
#include <utility>
#include <stdint.h>
#include <stddef.h>

#define TOKENS 8192
#define CDIM 2048
#define FDIM 8192
#define EPSV 1.1920929e-07f

typedef __attribute__((ext_vector_type(8))) short short8;
typedef __attribute__((ext_vector_type(8))) __bf16 bf16x8;
typedef __attribute__((ext_vector_type(4))) float floatx4;

// Detect which operand typing this clang uses for the gfx950 bf16 MFMA builtin.
template <typename V, typename = void> struct CanMfma : std::false_type {};
template <typename V>
struct CanMfma<V, std::void_t<decltype(__builtin_amdgcn_mfma_f32_16x16x32_bf16(
    std::declval<V>(), std::declval<V>(), std::declval<floatx4>(), 0, 0, 0))>>
    : std::true_type {};
using frag_t = std::conditional_t<CanMfma<short8>::value, short8, bf16x8>;

__device__ __forceinline__ floatx4 mfma_bf16(frag_t a, frag_t b, floatx4 c) {
    return __builtin_amdgcn_mfma_f32_16x16x32_bf16(a, b, c, 0, 0, 0);
}

// round-to-nearest-even f32 -> bf16
__device__ __forceinline__ unsigned short f2bf(float f) {
    unsigned int u = __float_as_uint(f);
    u += 0x7fffu + ((u >> 16) & 1u);
    return (unsigned short)(u >> 16);
}

__global__ void zero_kernel(int* p) { if (threadIdx.x == 0) *p = 0; }

// Convert both weight matrices fp32 -> bf16 in one launch.
__global__ __launch_bounds__(256) void cvt2_kernel(
    const float* __restrict__ s1, unsigned short* __restrict__ d1, int n1,
    const float* __restrict__ s2, unsigned short* __restrict__ d2, int n2)
{
    int i = blockIdx.x * 256 + threadIdx.x;
    const float4* s; ushort4* d;
    if (i < n1) { s = (const float4*)s1; d = (ushort4*)d1; }
    else if (i < n1 + n2) { s = (const float4*)s2; d = (ushort4*)d2; i -= n1; }
    else return;
    float4 v = s[i];
    ushort4 o;
    o.x = f2bf(v.x); o.y = f2bf(v.y); o.z = f2bf(v.z); o.w = f2bf(v.w);
    d[i] = o;
}

// Per token: router logit, sigmoid mask, RMSNorm; compact selected tokens into
// Xn (bf16). ALL tokens get out = x (residual base); GEMM2 atomic-adds the
// gated MLP on top for selected tokens.
__global__ __launch_bounds__(256) void router_kernel(
    const float* __restrict__ x, const float* __restrict__ wr,
    float* __restrict__ out, unsigned short* __restrict__ Xn,
    int* __restrict__ idx, float* __restrict__ mv, int* __restrict__ cnt)
{
    const int token = blockIdx.x;
    const int tid = threadIdx.x;
    const float4* xr = (const float4*)(x + (size_t)token * CDIM);
    const float4* w4 = (const float4*)wr;
    float4 a0 = xr[tid];
    float4 a1 = xr[tid + 256];
    float4 b0 = w4[tid];
    float4 b1 = w4[tid + 256];
    float ss = a0.x*a0.x + a0.y*a0.y + a0.z*a0.z + a0.w*a0.w
             + a1.x*a1.x + a1.y*a1.y + a1.z*a1.z + a1.w*a1.w;
    float dt = a0.x*b0.x + a0.y*b0.y + a0.z*b0.z + a0.w*b0.w
             + a1.x*b1.x + a1.y*b1.y + a1.z*b1.z + a1.w*b1.w;
    #pragma unroll
    for (int off = 32; off > 0; off >>= 1) {
        ss += __shfl_down(ss, off);
        dt += __shfl_down(dt, off);
    }
    __shared__ float red_ss[4], red_dt[4];
    __shared__ float s_rms;
    __shared__ int s_pos;
    const int wave = tid >> 6;
    if ((tid & 63) == 0) { red_ss[wave] = ss; red_dt[wave] = dt; }
    __syncthreads();
    if (tid == 0) {
        float S = red_ss[0] + red_ss[1] + red_ss[2] + red_ss[3];
        float D = red_dt[0] + red_dt[1] + red_dt[2] + red_dt[3];
        float prob = 1.0f / (1.0f + expf(-D));
        s_rms = 1.0f / sqrtf(S * (1.0f / (float)CDIM) + EPSV);
        int pos = -1;
        if (prob > 0.5f) {
            pos = atomicAdd(cnt, 1);
            idx[pos] = token;
            mv[pos] = (1.0f + prob) - prob;  // replicate STE mask_i rounding exactly
        }
        s_pos = pos;
    }
    __syncthreads();
    // residual base for ALL tokens
    float4* op = (float4*)(out + (size_t)token * CDIM);
    op[tid] = a0;
    op[tid + 256] = a1;
    const float rms = s_rms;
    const int pos = s_pos;
    if (pos >= 0) {
        ushort4* xp = (ushort4*)(Xn + (size_t)pos * CDIM);
        ushort4 o;
        o.x = f2bf(a0.x * rms); o.y = f2bf(a0.y * rms); o.z = f2bf(a0.z * rms); o.w = f2bf(a0.w * rms);
        xp[tid] = o;
        o.x = f2bf(a1.x * rms); o.y = f2bf(a1.y * rms); o.z = f2bf(a1.z * rms); o.w = f2bf(a1.w * rms);
        xp[tid + 256] = o;
    }
}

// C[m][n] = sum_k A[m][k]*B[n][k], A:[M][K] bf16 (compacted rows), B:[N][K] bf16.
// 128x128 tile, BK=64, 4 waves 2x2, 4x4 MFMA 16x16x32; global_load_lds(16B)
// staging with XOR swizzle on the GLOBAL address side.
//
// 8x8 SUPERTILE raster: 64 consecutive blocks cover 8 m-panels x 8 n-panels,
// so each per-kt A-chunk and B-chunk is shared by ~8 temporally-adjacent
// blocks (L2-hit latency instead of one operand HBM-cold each kt; rounds 1-2
// showed 17-18% MfmaUtil pinned regardless of FETCH -> latency-bound drain).
// KSPLIT: blockIdx.z takes K-chunk [z*K/KSPLIT, ...); MODE 2 atomic-adds.
// MODE 1: Hout[m][n] = bf16(relu(acc)^2).  MODE 2: atomicAdd scale*acc to out.
template <int K, int MODE, int LDO, int KSPLIT>
__global__ __launch_bounds__(256) void gemm_bt(
    const unsigned short* __restrict__ A,
    const unsigned short* __restrict__ B,
    unsigned short* __restrict__ Hout,
    float* __restrict__ out,
    const int* __restrict__ idx,
    const float* __restrict__ mv,
    const int* __restrict__ cntp)
{
    const int cnt = *cntp;
    // supertile swizzle (gridDim.x == 64 m-panels for both GEMMs)
    const int bid = blockIdx.y * 64 + blockIdx.x;
    const int s = bid >> 6;          // supertile id
    const int w = bid & 63;          // position within 8x8 supertile
    const int mi = (s & 7) * 8 + (w & 7);    // Mp=64 -> 8 supertile rows, m-fastest
    const int ni = (s >> 3) * 8 + (w >> 3);
    const int m0 = mi * 128;
    if (m0 >= cnt) return;
    const int n0 = ni * 128;
    const int k0 = (int)blockIdx.z * (K / KSPLIT);   // element offset in k

    __shared__ alignas(16) unsigned short lA[128 * 64];
    __shared__ alignas(16) unsigned short lB[128 * 64];

    const int tid = threadIdx.x;
    const int wave = tid >> 6;
    const int lane = tid & 63;
    const int wm = (wave >> 1) * 64;
    const int wn = (wave & 1) * 64;
    const int quad = lane >> 4;
    const int l16 = lane & 15;

    // staging: wave w, issue p covers rows p*32+w*8 .. +8; lane i -> row +i/8,
    // global 16B chunk (i&7)^(i/8) (swizzle), LDS chunk i&7 (hardware lane order)
    const int srow = lane >> 3;
    const int schunk = (lane & 7) ^ srow;

    const unsigned short* ap[4];
    const unsigned short* bp[4];
    #pragma unroll
    for (int p = 0; p < 4; ++p) {
        const int r = p * 32 + wave * 8 + srow;
        ap[p] = A + (size_t)(m0 + r) * K + k0 + schunk * 8;
        bp[p] = B + (size_t)(n0 + r) * K + k0 + schunk * 8;
    }

    floatx4 acc[4][4] = {};

    for (int kt = 0; kt < K / (64 * KSPLIT); ++kt) {
        #pragma unroll
        for (int p = 0; p < 4; ++p) {
            __builtin_amdgcn_global_load_lds(
                (__attribute__((address_space(1))) void*)ap[p],
                (__attribute__((address_space(3))) void*)&lA[(p * 32 + wave * 8) * 64],
                16, 0, 0);
            __builtin_amdgcn_global_load_lds(
                (__attribute__((address_space(1))) void*)bp[p],
                (__attribute__((address_space(3))) void*)&lB[(p * 32 + wave * 8) * 64],
                16, 0, 0);
            ap[p] += 64;
            bp[p] += 64;
        }
        __syncthreads();  // drains vmcnt before LDS reads
        #pragma unroll
        for (int st = 0; st < 2; ++st) {
            frag_t af[4], bfv[4];
            #pragma unroll
            for (int t = 0; t < 4; ++t) {
                const int ra = wm + t * 16 + l16;
                const int ca = ((st * 4 + quad) ^ (ra & 7)) * 8;
                af[t] = *(const frag_t*)&lA[ra * 64 + ca];
                const int rb = wn + t * 16 + l16;
                const int cb = ((st * 4 + quad) ^ (rb & 7)) * 8;
                bfv[t] = *(const frag_t*)&lB[rb * 64 + cb];
            }
            #pragma unroll
            for (int tm = 0; tm < 4; ++tm)
                #pragma unroll
                for (int tn = 0; tn < 4; ++tn)
                    acc[tm][tn] = mfma_bf16(af[tm], bfv[tn], acc[tm][tn]);
        }
        __syncthreads();
    }

    // C/D layout (verified m89/m91): col(n) = lane&15, row(m) = quad*4 + reg
    if (MODE == 1) {
        #pragma unroll
        for (int tm = 0; tm < 4; ++tm) {
            const int gm = m0 + wm + tm * 16 + quad * 4;
            #pragma unroll
            for (int tn = 0; tn < 4; ++tn) {
                const int gn = n0 + wn + tn * 16 + l16;
                #pragma unroll
                for (int v = 0; v < 4; ++v) {
                    float h = fmaxf(acc[tm][tn][v], 0.0f);  // fmax eats NaN pad rows too
                    Hout[(size_t)(gm + v) * LDO + gn] = f2bf(h * h);
                }
            }
        }
    } else {
        #pragma unroll
        for (int tm = 0; tm < 4; ++tm) {
            const int gmb = m0 + wm + tm * 16 + quad * 4;
            #pragma unroll
            for (int v = 0; v < 4; ++v) {
                const int gm = gmb + v;
                if (gm < cnt) {  // never read poisoned idx/mv beyond cnt
                    const int token = idx[gm];
                    const float scale = mv[gm];
                    #pragma unroll
                    for (int tn = 0; tn < 4; ++tn) {
                        const int gn = n0 + wn + tn * 16 + l16;
                        atomicAdd(&out[(size_t)token * LDO + gn], scale * acc[tm][tn][v]);
                    }
                }
            }
        }
    }
}

extern "C" void kernel_launch(void* const* d_in, const int* in_sizes, int n_in,
                              void* d_out, int out_size, void* d_ws, size_t ws_size,
                              hipStream_t stream)
{
    const float* x   = (const float*)d_in[0];
    const float* wfc = (const float*)d_in[1];
    const float* wpr = (const float*)d_in[2];
    const float* wrt = (const float*)d_in[3];
    float* out = (float*)d_out;

    // ws layout (bytes): [cnt 256][idx 32K][mv 32K][Xn 32M][Wfc 32M][Wpr 32M][H 128M]
    char* ws = (char*)d_ws;
    int*   cnt = (int*)ws;
    int*   idx = (int*)(ws + 256);
    float* mv  = (float*)(ws + 256 + 32768);
    unsigned short* Xn  = (unsigned short*)(ws + 65792);
    unsigned short* Wfc = (unsigned short*)(ws + 65792 + 33554432ULL);
    unsigned short* Wpr = (unsigned short*)(ws + 65792 + 67108864ULL);
    unsigned short* H   = (unsigned short*)(ws + 65792 + 100663296ULL);

    const int n4 = FDIM * CDIM / 4;  // float4 count per weight matrix
    zero_kernel<<<1, 64, 0, stream>>>(cnt);
    cvt2_kernel<<<(2 * n4 + 255) / 256, 256, 0, stream>>>(wfc, Wfc, n4, wpr, Wpr, n4);
    router_kernel<<<TOKENS, 256, 0, stream>>>(x, wrt, out, Xn, idx, mv, cnt);
    // GEMM1: H[m][f] = relu(Xn @ Wfc^T)^2, M=cnt (<=8192), N=8192, K=2048
    gemm_bt<CDIM, 1, FDIM, 1><<<dim3(64, FDIM / 128), 256, 0, stream>>>(
        Xn, Wfc, H, nullptr, nullptr, nullptr, cnt);
    // GEMM2: out[token][c] += mask_i * (H @ Wpr^T), M=cnt, N=2048, K=8192, split-K x2
    gemm_bt<FDIM, 2, CDIM, 2><<<dim3(64, CDIM / 128, 2), 256, 0, stream>>>(
        H, Wpr, nullptr, out, idx, mv, cnt);
}